// Round 10
// baseline (394.375 us; speedup 1.0000x reference)
//
#include <hip/hip_runtime.h>
#include <hip/hip_bf16.h>

typedef _Float16 f16x8 __attribute__((ext_vector_type(8)));
typedef unsigned short u16x8 __attribute__((ext_vector_type(8)));
typedef float f32x4 __attribute__((ext_vector_type(4)));

static __device__ __forceinline__ unsigned short h2u(_Float16 h) {
    return __builtin_bit_cast(unsigned short, h);
}
static __device__ __forceinline__ float fast_tanh(float x) {
    float e = __expf(2.0f * x);
    return 1.0f - 2.0f / (e + 1.0f);
}

// ---------------- ws layout (bytes) ----------------
//   wlin_h : u16 [320][512]   @ 0        (327680)
//   wlin_l : u16 [320][512]   @ 327680   (327680)
//   wnlm   : f32 [255][256]   @ 655360   (261120)
//   wnl_h  : u16 [255][256]   @ 916480   (130560)
//   wnl_l  : u16 [255][256]   @ 1047040  (130560)
//   wout_h : u16 [64][256]    @ 1177600  (32768)
//   wout_l : u16 [64][256]    @ 1210368  (32768)
//   wtri   : f32 [8][496]     @ 1243136  (15872)   compact intra-block triangles
//   linc   : f32 [65536][256] @ 1259008  (67108864)
//   lino   : f32 [65536][64]  @ 68367872 (16777216)  total 85145088
__global__ void cascade_prep(const float* __restrict__ W_lin,
                             const float* __restrict__ W_nl,
                             const float* __restrict__ W_out,
                             unsigned short* __restrict__ wlin_h,
                             unsigned short* __restrict__ wlin_l,
                             float* __restrict__ wnlm,
                             unsigned short* __restrict__ wnl_h,
                             unsigned short* __restrict__ wnl_l,
                             unsigned short* __restrict__ wout_h,
                             unsigned short* __restrict__ wout_l,
                             float* __restrict__ wtri) {
    int idx = blockIdx.x * blockDim.x + threadIdx.x;
    int stride = gridDim.x * blockDim.x;
    for (int i = idx; i < 320 * 512; i += stride) {
        int n = i >> 9, k = i & 511;
        float w = W_lin[k * 320 + n];
        _Float16 h = (_Float16)w;
        wlin_h[i] = h2u(h);
        wlin_l[i] = h2u((_Float16)(w - (float)h));
    }
    for (int i = idx; i < 255 * 256; i += stride) {
        int r = i >> 8, k = i & 255;
        float w = (k <= r) ? W_nl[i] : 0.0f;
        wnlm[i] = w;
        _Float16 h = (_Float16)w;
        wnl_h[i] = h2u(h);
        wnl_l[i] = h2u((_Float16)(w - (float)h));
    }
    for (int i = idx; i < 64 * 256; i += stride) {
        float w = W_out[i];
        _Float16 h = (_Float16)w;
        wout_h[i] = h2u(h);
        wout_l[i] = h2u((_Float16)(w - (float)h));
    }
    // compact intra-block triangular weights: wtri[b][u*(u-1)/2 + c] =
    // W_nl[(32b+u-1)*256 + 32b + c], u in [1,32), c < u  (mask trivially true)
    for (int i = idx; i < 256; i += stride) {
        int b = i >> 5, u = i & 31;
        if (u >= 1) {
            float* dst = wtri + b * 496 + (u * (u - 1)) / 2;
            const float* src = W_nl + (size_t)(b * 32 + u - 1) * 256 + b * 32;
            for (int c = 0; c < u; ++c) dst[c] = src[c];
        }
    }
}

// ---------------- kernel A: lin = x @ W_lin (fp16-split), writes linc/lino ----------------
// 256 threads, 32 rows/block. LDS x hi/lo [32][520] fp16 = 66560 B -> 2 blocks/CU.
__global__ __launch_bounds__(256, 2) void lin_gemm(
    const float* __restrict__ x,
    const unsigned short* __restrict__ wlin_h,
    const unsigned short* __restrict__ wlin_l,
    float* __restrict__ linc,
    float* __restrict__ lino) {

    __shared__ _Float16 xh[32 * 520];
    __shared__ _Float16 xl[32 * 520];

    const int tid = threadIdx.x;
    const int wv  = tid >> 6;
    const int l15 = tid & 15;
    const int g   = (tid & 63) >> 4;
    const long row0 = (long)blockIdx.x * 32;

    #pragma unroll
    for (int it = 0; it < 16; ++it) {
        int flat = it * 1024 + tid * 4;
        int r = flat >> 9, c = flat & 511;
        float4 v = *reinterpret_cast<const float4*>(x + (row0 + r) * 512 + c);
        _Float16 h0 = (_Float16)v.x, h1 = (_Float16)v.y, h2 = (_Float16)v.z, h3 = (_Float16)v.w;
        ushort4 uh = { h2u(h0), h2u(h1), h2u(h2), h2u(h3) };
        ushort4 ul = { h2u((_Float16)(v.x - (float)h0)), h2u((_Float16)(v.y - (float)h1)),
                       h2u((_Float16)(v.z - (float)h2)), h2u((_Float16)(v.w - (float)h3)) };
        *reinterpret_cast<ushort4*>(xh + r * 520 + c) = uh;
        *reinterpret_cast<ushort4*>(xl + r * 520 + c) = ul;
    }
    __syncthreads();

    f32x4 acc[2][5];
    #pragma unroll
    for (int m = 0; m < 2; ++m)
        #pragma unroll
        for (int ti = 0; ti < 5; ++ti) acc[m][ti] = (f32x4){0.f, 0.f, 0.f, 0.f};

    for (int half = 0; half < 2; ++half) {
        f16x8 ah[2][8], al[2][8];
        #pragma unroll
        for (int m = 0; m < 2; ++m)
            #pragma unroll
            for (int k8 = 0; k8 < 8; ++k8) {
                int off = (m * 16 + l15) * 520 + g * 8 + (half * 8 + k8) * 32;
                ah[m][k8] = *reinterpret_cast<const f16x8*>(xh + off);
                al[m][k8] = *reinterpret_cast<const f16x8*>(xl + off);
            }
        #pragma unroll
        for (int ti = 0; ti < 5; ++ti) {
            int n = wv + ti * 4;
            const unsigned short* bhp = wlin_h + (size_t)(n * 16 + l15) * 512 + g * 8 + half * 256;
            const unsigned short* blp = wlin_l + (size_t)(n * 16 + l15) * 512 + g * 8 + half * 256;
            #pragma unroll
            for (int k8 = 0; k8 < 8; ++k8) {
                f16x8 bh = __builtin_bit_cast(f16x8, *reinterpret_cast<const u16x8*>(bhp + k8 * 32));
                #pragma unroll
                for (int m = 0; m < 2; ++m)
                    acc[m][ti] = __builtin_amdgcn_mfma_f32_16x16x32_f16(ah[m][k8], bh, acc[m][ti], 0, 0, 0);
                if (ti < 4) {
                    f16x8 bl = __builtin_bit_cast(f16x8, *reinterpret_cast<const u16x8*>(blp + k8 * 32));
                    #pragma unroll
                    for (int m = 0; m < 2; ++m) {
                        acc[m][ti] = __builtin_amdgcn_mfma_f32_16x16x32_f16(al[m][k8], bh, acc[m][ti], 0, 0, 0);
                        acc[m][ti] = __builtin_amdgcn_mfma_f32_16x16x32_f16(ah[m][k8], bl, acc[m][ti], 0, 0, 0);
                    }
                }
            }
        }
    }
    #pragma unroll
    for (int m = 0; m < 2; ++m) {
        #pragma unroll
        for (int ti = 0; ti < 4; ++ti) {
            int c = (wv + ti * 4) * 16 + l15;
            #pragma unroll
            for (int j = 0; j < 4; ++j)
                linc[(row0 + m * 16 + g * 4 + j) * 256 + c] = acc[m][ti][j];
        }
        int c = wv * 16 + l15;
        #pragma unroll
        for (int j = 0; j < 4; ++j)
            lino[(row0 + m * 16 + g * 4 + j) * 64 + c] = acc[m][4][j];
    }
}

// ---------------- kernel B: cascade + output GEMM ----------------
// 1 wave, 16 rows/block. LDS: conT 2304 + linT 2304 = 4608 B.
// __launch_bounds__(64,3): VGPR cap ~170 so the ~120-reg working set does NOT
// spill (round 7's (64,4) made the allocator demote th/hh/ll to scratch:
// VGPR=64, +26MB scratch writes). Natural allocation ~120 <= 128 still gives
// 4 waves/SIMD (16 blocks/CU, all 4096 waves resident in one round).
__global__ __launch_bounds__(64, 3) void cascade_casc(
    const float* __restrict__ linc,
    const float* __restrict__ lino,
    const float* __restrict__ wtri,
    const unsigned short* __restrict__ wnl_h,
    const unsigned short* __restrict__ wnl_l,
    const unsigned short* __restrict__ wout_h,
    const unsigned short* __restrict__ wout_l,
    float* __restrict__ out) {

    __shared__ float conT[16 * 36];   // [row][u] contrib window / pack scratch
    __shared__ float linT[16 * 36];   // [row][u] lin window

    const int l   = threadIdx.x;
    const int l15 = l & 15;
    const int g   = l >> 4;
    const long row0 = (long)blockIdx.x * 16;

    f16x8 hh[8];   // fp16 hi history (lane's own row, g-slice) — static idx only
    f16x8 ll[8];   // fp16 lo history — static idx only
    float th[32];  // current block tanh f32 (replicated across g) — static idx only
    float carry = 0.0f;

    #pragma unroll
    for (int b = 0; b < 8; ++b) {
        // --- stage lin window [16 rows][32 cols] -> linT ---
        {
            int rr = l >> 2, c8 = (l & 3) * 8;
            const float* lp = linc + (row0 + rr) * 256 + b * 32 + c8;
            float4 v0 = *reinterpret_cast<const float4*>(lp);
            float4 v1 = *reinterpret_cast<const float4*>(lp + 4);
            *reinterpret_cast<float4*>(&linT[rr * 36 + c8]) = v0;
            *reinterpret_cast<float4*>(&linT[rr * 36 + c8 + 4]) = v1;
        }

        // --- inter-block contribution GEMM (K = 32b), history from registers ---
        f32x4 accC[2];
        accC[0] = (f32x4){0.f, 0.f, 0.f, 0.f};
        accC[1] = (f32x4){0.f, 0.f, 0.f, 0.f};
        #pragma unroll
        for (int kc = 0; kc < 7; ++kc) {
            if (kc < b) {
                f16x8 ah = hh[kc];
                f16x8 al = ll[kc];
                #pragma unroll
                for (int n2 = 0; n2 < 2; ++n2) {
                    const size_t wrow = (size_t)(b * 32 + n2 * 16 + l15 - 1) * 256 + kc * 32 + g * 8;
                    f16x8 bh = __builtin_bit_cast(f16x8, *reinterpret_cast<const u16x8*>(wnl_h + wrow));
                    f16x8 bl = __builtin_bit_cast(f16x8, *reinterpret_cast<const u16x8*>(wnl_l + wrow));
                    accC[n2] = __builtin_amdgcn_mfma_f32_16x16x32_f16(ah, bh, accC[n2], 0, 0, 0);
                    accC[n2] = __builtin_amdgcn_mfma_f32_16x16x32_f16(al, bh, accC[n2], 0, 0, 0);
                    accC[n2] = __builtin_amdgcn_mfma_f32_16x16x32_f16(ah, bl, accC[n2], 0, 0, 0);
                }
            }
        }
        // bounce D-frags -> conT[row][col]
        #pragma unroll
        for (int n2 = 0; n2 < 2; ++n2)
            #pragma unroll
            for (int j = 0; j < 4; ++j)
                conT[(g * 4 + j) * 36 + n2 * 16 + l15] = accC[n2][j];
        __syncthreads();

        if (b == 0) carry = linT[l15 * 36];   // lin[row, 0] for neuron 0

        // --- serial 32 steps; all operands registers / scalar loads ---
        float lastlin = carry;
        #pragma unroll
        for (int u8 = 0; u8 < 4; ++u8) {
            float4 cw0 = *reinterpret_cast<const float4*>(&conT[l15 * 36 + u8 * 8]);
            float4 cw1 = *reinterpret_cast<const float4*>(&conT[l15 * 36 + u8 * 8 + 4]);
            float4 lw0 = *reinterpret_cast<const float4*>(&linT[l15 * 36 + u8 * 8]);
            float4 lw1 = *reinterpret_cast<const float4*>(&linT[l15 * 36 + u8 * 8 + 4]);
            float conw[8] = {cw0.x, cw0.y, cw0.z, cw0.w, cw1.x, cw1.y, cw1.z, cw1.w};
            float linw[8] = {lw0.x, lw0.y, lw0.z, lw0.w, lw1.x, lw1.y, lw1.z, lw1.w};
            #pragma unroll
            for (int v = 0; v < 8; ++v) {
                const int u = u8 * 8 + v;
                float pa = 0.0f;
                if (u > 0) {
                    // compact triangular slab, contiguous, uniform address -> s_load
                    const float* wr = wtri + b * 496 + (u * (u - 1)) / 2;
                    float p0 = 0.f, p1 = 0.f, p2 = 0.f, p3 = 0.f;
                    #pragma unroll
                    for (int c = 0; c + 3 < u; c += 4) {
                        p0 = fmaf(th[c],     wr[c],     p0);
                        p1 = fmaf(th[c + 1], wr[c + 1], p1);
                        p2 = fmaf(th[c + 2], wr[c + 2], p2);
                        p3 = fmaf(th[c + 3], wr[c + 3], p3);
                    }
                    #pragma unroll
                    for (int c = u & ~3; c < u; ++c)
                        p0 = fmaf(th[c], wr[c], p0);
                    pa = (p0 + p1) + (p2 + p3);
                }
                float lv = (v == 0) ? lastlin : linw[v - 1];
                float vv = pa + conw[v] + lv + 1.0f;
                th[u] = fast_tanh(vv);
            }
            lastlin = linw[7];
        }
        carry = lastlin;

        // --- pack history via LDS bounce (g-slice needs cross-lane transpose) ---
        __syncthreads();
        if (l < 16) {
            #pragma unroll
            for (int c8 = 0; c8 < 32; c8 += 4)
                *reinterpret_cast<float4*>(&conT[l15 * 36 + c8]) =
                    (float4){th[c8], th[c8 + 1], th[c8 + 2], th[c8 + 3]};
        }
        __syncthreads();
        float4 s0 = *reinterpret_cast<const float4*>(&conT[l15 * 36 + g * 8]);
        float4 s1 = *reinterpret_cast<const float4*>(&conT[l15 * 36 + g * 8 + 4]);
        float sv[8] = {s0.x, s0.y, s0.z, s0.w, s1.x, s1.y, s1.z, s1.w};
        f16x8 fh, fl;
        #pragma unroll
        for (int e = 0; e < 8; ++e) {
            _Float16 hv = (_Float16)sv[e];
            fh[e] = hv;
            fl[e] = (_Float16)(sv[e] - (float)hv);
        }
        hh[b] = fh;
        ll[b] = fl;
        __syncthreads();
    }

    // ===== stage 3: out = tanh @ W_out^T + lin_o + 1 =====
    #pragma unroll
    for (int n = 0; n < 4; ++n) {
        f32x4 acc = (f32x4){0.f, 0.f, 0.f, 0.f};
        #pragma unroll
        for (int kc = 0; kc < 8; ++kc) {
            const size_t wrow = (size_t)(n * 16 + l15) * 256 + kc * 32 + g * 8;
            f16x8 bh = __builtin_bit_cast(f16x8, *reinterpret_cast<const u16x8*>(wout_h + wrow));
            f16x8 bl = __builtin_bit_cast(f16x8, *reinterpret_cast<const u16x8*>(wout_l + wrow));
            acc = __builtin_amdgcn_mfma_f32_16x16x32_f16(hh[kc], bh, acc, 0, 0, 0);
            acc = __builtin_amdgcn_mfma_f32_16x16x32_f16(ll[kc], bh, acc, 0, 0, 0);
            acc = __builtin_amdgcn_mfma_f32_16x16x32_f16(hh[kc], bl, acc, 0, 0, 0);
        }
        #pragma unroll
        for (int j = 0; j < 4; ++j) {
            long r = row0 + g * 4 + j;
            int c = n * 16 + l15;
            out[r * 64 + c] = acc[j] + lino[r * 64 + c] + 1.0f;
        }
    }
}

extern "C" void kernel_launch(void* const* d_in, const int* in_sizes, int n_in,
                              void* d_out, int out_size, void* d_ws, size_t ws_size,
                              hipStream_t stream) {
    (void)in_sizes; (void)n_in; (void)out_size; (void)ws_size;
    const float* x     = (const float*)d_in[0];
    const float* W_lin = (const float*)d_in[1];
    const float* W_nl  = (const float*)d_in[2];
    const float* W_out = (const float*)d_in[3];
    float* out = (float*)d_out;

    char* ws = (char*)d_ws;
    unsigned short* wlin_h = (unsigned short*)(ws);
    unsigned short* wlin_l = (unsigned short*)(ws + 327680);
    float*          wnlm   = (float*)(ws + 655360);
    unsigned short* wnl_h  = (unsigned short*)(ws + 916480);
    unsigned short* wnl_l  = (unsigned short*)(ws + 1047040);
    unsigned short* wout_h = (unsigned short*)(ws + 1177600);
    unsigned short* wout_l = (unsigned short*)(ws + 1210368);
    float*          wtri   = (float*)(ws + 1243136);
    float*          linc   = (float*)(ws + 1259008);
    float*          lino   = (float*)(ws + 68367872);

    cascade_prep<<<256, 256, 0, stream>>>(W_lin, W_nl, W_out,
                                          wlin_h, wlin_l, wnlm, wnl_h, wnl_l,
                                          wout_h, wout_l, wtri);
    lin_gemm<<<65536 / 32, 256, 0, stream>>>(x, wlin_h, wlin_l, linc, lino);
    cascade_casc<<<65536 / 16, 64, 0, stream>>>(linc, lino, wtri,
                                                wnl_h, wnl_l, wout_h, wout_l, out);
}

// Round 11
// 339.476 us; speedup vs baseline: 1.1617x; 1.1617x over previous
//
#include <hip/hip_runtime.h>
#include <hip/hip_bf16.h>

typedef _Float16 f16x8 __attribute__((ext_vector_type(8)));
typedef unsigned short u16x8 __attribute__((ext_vector_type(8)));
typedef float f32x4 __attribute__((ext_vector_type(4)));
typedef unsigned int u32x4 __attribute__((ext_vector_type(4)));

static __device__ __forceinline__ unsigned short h2u(_Float16 h) {
    return __builtin_bit_cast(unsigned short, h);
}
static __device__ __forceinline__ float fast_tanh(float x) {
    float e = __expf(2.0f * x);
    return 1.0f - 2.0f / (e + 1.0f);
}

// ---------------- ws layout (bytes) ----------------
//   wlin_h : u16 [320][512]   @ 0        (327680)
//   wlin_l : u16 [320][512]   @ 327680   (327680)
//   (unused: old wnlm slot)   @ 655360   (261120)
//   wnl_h  : u16 [255][256]   @ 916480   (130560)
//   wnl_l  : u16 [255][256]   @ 1047040  (130560)
//   wout_h : u16 [64][256]    @ 1177600  (32768)
//   wout_l : u16 [64][256]    @ 1210368  (32768)
//   wcol   : f32 [8][496]     @ 1243136  (15872)   column-transposed triangles
//   linc   : f32 [65536][256] @ 1259008  (67108864)  (overlaid by packed hist)
//   lino   : f32 [65536][64]  @ 68367872 (16777216)  total 85145088
__global__ void cascade_prep(const float* __restrict__ W_lin,
                             const float* __restrict__ W_nl,
                             const float* __restrict__ W_out,
                             unsigned short* __restrict__ wlin_h,
                             unsigned short* __restrict__ wlin_l,
                             unsigned short* __restrict__ wnl_h,
                             unsigned short* __restrict__ wnl_l,
                             unsigned short* __restrict__ wout_h,
                             unsigned short* __restrict__ wout_l,
                             float* __restrict__ wcol) {
    int idx = blockIdx.x * blockDim.x + threadIdx.x;
    int stride = gridDim.x * blockDim.x;
    for (int i = idx; i < 320 * 512; i += stride) {
        int n = i >> 9, k = i & 511;
        float w = W_lin[k * 320 + n];
        _Float16 h = (_Float16)w;
        wlin_h[i] = h2u(h);
        wlin_l[i] = h2u((_Float16)(w - (float)h));
    }
    for (int i = idx; i < 255 * 256; i += stride) {
        int r = i >> 8, k = i & 255;
        float w = (k <= r) ? W_nl[i] : 0.0f;
        _Float16 h = (_Float16)w;
        wnl_h[i] = h2u(h);
        wnl_l[i] = h2u((_Float16)(w - (float)h));
    }
    for (int i = idx; i < 64 * 256; i += stride) {
        float w = W_out[i];
        _Float16 h = (_Float16)w;
        wout_h[i] = h2u(h);
        wout_l[i] = h2u((_Float16)(w - (float)h));
    }
    // column-transposed intra-block triangles:
    // wcol[b][31u - u(u-1)/2 + (j-u-1)] = W_nl[32b+j-1][32b+u], j in (u,32)
    for (int i = idx; i < 256; i += stride) {
        int b = i >> 5, u = i & 31;
        float* dst = wcol + b * 496 + (31 * u - (u * (u - 1)) / 2);
        for (int j = u + 1; j < 32; ++j)
            dst[j - u - 1] = W_nl[(size_t)(b * 32 + j - 1) * 256 + b * 32 + u];
    }
}

// ---------------- kernel A: lin = x @ W_lin (fp16-split), writes linc/lino ----------------
// 256 threads, 32 rows/block. LDS x hi/lo [32][520] fp16 = 66560 B -> 2 blocks/CU.
__global__ __launch_bounds__(256, 2) void lin_gemm(
    const float* __restrict__ x,
    const unsigned short* __restrict__ wlin_h,
    const unsigned short* __restrict__ wlin_l,
    float* __restrict__ linc,
    float* __restrict__ lino) {

    __shared__ _Float16 xh[32 * 520];
    __shared__ _Float16 xl[32 * 520];

    const int tid = threadIdx.x;
    const int wv  = tid >> 6;
    const int l15 = tid & 15;
    const int g   = (tid & 63) >> 4;
    const long row0 = (long)blockIdx.x * 32;

    #pragma unroll
    for (int it = 0; it < 16; ++it) {
        int flat = it * 1024 + tid * 4;
        int r = flat >> 9, c = flat & 511;
        float4 v = *reinterpret_cast<const float4*>(x + (row0 + r) * 512 + c);
        _Float16 h0 = (_Float16)v.x, h1 = (_Float16)v.y, h2 = (_Float16)v.z, h3 = (_Float16)v.w;
        ushort4 uh = { h2u(h0), h2u(h1), h2u(h2), h2u(h3) };
        ushort4 ul = { h2u((_Float16)(v.x - (float)h0)), h2u((_Float16)(v.y - (float)h1)),
                       h2u((_Float16)(v.z - (float)h2)), h2u((_Float16)(v.w - (float)h3)) };
        *reinterpret_cast<ushort4*>(xh + r * 520 + c) = uh;
        *reinterpret_cast<ushort4*>(xl + r * 520 + c) = ul;
    }
    __syncthreads();

    f32x4 acc[2][5];
    #pragma unroll
    for (int m = 0; m < 2; ++m)
        #pragma unroll
        for (int ti = 0; ti < 5; ++ti) acc[m][ti] = (f32x4){0.f, 0.f, 0.f, 0.f};

    for (int half = 0; half < 2; ++half) {
        f16x8 ah[2][8], al[2][8];
        #pragma unroll
        for (int m = 0; m < 2; ++m)
            #pragma unroll
            for (int k8 = 0; k8 < 8; ++k8) {
                int off = (m * 16 + l15) * 520 + g * 8 + (half * 8 + k8) * 32;
                ah[m][k8] = *reinterpret_cast<const f16x8*>(xh + off);
                al[m][k8] = *reinterpret_cast<const f16x8*>(xl + off);
            }
        #pragma unroll
        for (int ti = 0; ti < 5; ++ti) {
            int n = wv + ti * 4;
            const unsigned short* bhp = wlin_h + (size_t)(n * 16 + l15) * 512 + g * 8 + half * 256;
            const unsigned short* blp = wlin_l + (size_t)(n * 16 + l15) * 512 + g * 8 + half * 256;
            #pragma unroll
            for (int k8 = 0; k8 < 8; ++k8) {
                f16x8 bh = __builtin_bit_cast(f16x8, *reinterpret_cast<const u16x8*>(bhp + k8 * 32));
                #pragma unroll
                for (int m = 0; m < 2; ++m)
                    acc[m][ti] = __builtin_amdgcn_mfma_f32_16x16x32_f16(ah[m][k8], bh, acc[m][ti], 0, 0, 0);
                if (ti < 4) {
                    f16x8 bl = __builtin_bit_cast(f16x8, *reinterpret_cast<const u16x8*>(blp + k8 * 32));
                    #pragma unroll
                    for (int m = 0; m < 2; ++m) {
                        acc[m][ti] = __builtin_amdgcn_mfma_f32_16x16x32_f16(al[m][k8], bh, acc[m][ti], 0, 0, 0);
                        acc[m][ti] = __builtin_amdgcn_mfma_f32_16x16x32_f16(ah[m][k8], bl, acc[m][ti], 0, 0, 0);
                    }
                }
            }
        }
    }
    #pragma unroll
    for (int m = 0; m < 2; ++m) {
        #pragma unroll
        for (int ti = 0; ti < 4; ++ti) {
            int c = (wv + ti * 4) * 16 + l15;
            #pragma unroll
            for (int j = 0; j < 4; ++j)
                linc[(row0 + m * 16 + g * 4 + j) * 256 + c] = acc[m][ti][j];
        }
        int c = wv * 16 + l15;
        #pragma unroll
        for (int j = 0; j < 4; ++j)
            lino[(row0 + m * 16 + g * 4 + j) * 64 + c] = acc[m][4][j];
    }
}

// unpack 8 packed h|l u32 columns -> fp16 hi / lo MFMA A-fragments
static __device__ __forceinline__ void hist_frag(const unsigned int* hp,
                                                 f16x8* ah, f16x8* al) {
    u32x4 a0 = *reinterpret_cast<const u32x4*>(hp);
    u32x4 a1 = *reinterpret_cast<const u32x4*>(hp + 4);
    u32x4 hx, lx;
    hx[0] = (a0[0] & 0xffffu) | (a0[1] << 16);
    hx[1] = (a0[2] & 0xffffu) | (a0[3] << 16);
    hx[2] = (a1[0] & 0xffffu) | (a1[1] << 16);
    hx[3] = (a1[2] & 0xffffu) | (a1[3] << 16);
    lx[0] = (a0[0] >> 16) | (a0[1] & 0xffff0000u);
    lx[1] = (a0[2] >> 16) | (a0[3] & 0xffff0000u);
    lx[2] = (a1[0] >> 16) | (a1[1] & 0xffff0000u);
    lx[3] = (a1[2] >> 16) | (a1[3] & 0xffff0000u);
    *ah = __builtin_bit_cast(f16x8, hx);
    *al = __builtin_bit_cast(f16x8, lx);
}

// ---------------- kernel B: cascade + output GEMM ----------------
// 1 wave, 16 rows/block. LDS: conT 2304 + linT 2304 = 4608 B.
// Serial phase is RANK-1 UPDATE form: acc[32] running partials; after th[u] is
// computed, scatter acc[j] += th[u]*wcol[u][j] (j>u) — dep chain = 1 FMA + tanh.
// Tanh history (fp16 h|l packed u32) is written OVER the consumed linc columns
// and re-read (L1/L2-hot) by the contribution GEMM and stage 3 — no th/hh/ll
// register arrays, working set ~90 VGPR -> no spill at (64,4), 16 blocks/CU.
__global__ __launch_bounds__(64, 4) void cascade_casc(
    float* linc,                        // f32 lin in, packed hist out (aliased!)
    const float* __restrict__ lino,
    const float* __restrict__ wcol,
    const unsigned short* __restrict__ wnl_h,
    const unsigned short* __restrict__ wnl_l,
    const unsigned short* __restrict__ wout_h,
    const unsigned short* __restrict__ wout_l,
    float* __restrict__ out) {

    __shared__ float conT[16 * 36];   // [row][u] contrib window
    __shared__ float linT[16 * 36];   // [row][u] lin window

    const int l   = threadIdx.x;
    const int l15 = l & 15;
    const int g   = l >> 4;
    const long row0 = (long)blockIdx.x * 16;

    unsigned int* histc = reinterpret_cast<unsigned int*>(linc);
    const long hrow = (row0 + l15) * 256;       // lane's history row base (cols)
    float carry = 0.0f;

    for (int b = 0; b < 8; ++b) {
        // --- stage lin window [16 rows][32 cols] -> linT (cols [32b,32b+32)) ---
        {
            int rr = l >> 2, c8 = (l & 3) * 8;
            const float* lp = linc + (row0 + rr) * 256 + b * 32 + c8;
            float4 v0 = *reinterpret_cast<const float4*>(lp);
            float4 v1 = *reinterpret_cast<const float4*>(lp + 4);
            *reinterpret_cast<float4*>(&linT[rr * 36 + c8]) = v0;
            *reinterpret_cast<float4*>(&linT[rr * 36 + c8 + 4]) = v1;
        }

        // --- inter-block contribution GEMM (K = 32b), A-frags from hist ---
        f32x4 accC[2];
        accC[0] = (f32x4){0.f, 0.f, 0.f, 0.f};
        accC[1] = (f32x4){0.f, 0.f, 0.f, 0.f};
        for (int kc = 0; kc < b; ++kc) {
            f16x8 ah, al;
            hist_frag(histc + hrow + kc * 32 + g * 8, &ah, &al);
            #pragma unroll
            for (int n2 = 0; n2 < 2; ++n2) {
                const size_t wrow = (size_t)(b * 32 + n2 * 16 + l15 - 1) * 256 + kc * 32 + g * 8;
                f16x8 bh = __builtin_bit_cast(f16x8, *reinterpret_cast<const u16x8*>(wnl_h + wrow));
                f16x8 bl = __builtin_bit_cast(f16x8, *reinterpret_cast<const u16x8*>(wnl_l + wrow));
                accC[n2] = __builtin_amdgcn_mfma_f32_16x16x32_f16(ah, bh, accC[n2], 0, 0, 0);
                accC[n2] = __builtin_amdgcn_mfma_f32_16x16x32_f16(al, bh, accC[n2], 0, 0, 0);
                accC[n2] = __builtin_amdgcn_mfma_f32_16x16x32_f16(ah, bl, accC[n2], 0, 0, 0);
            }
        }
        // bounce D-frags -> conT[row][col]
        #pragma unroll
        for (int n2 = 0; n2 < 2; ++n2)
            #pragma unroll
            for (int j = 0; j < 4; ++j)
                conT[(g * 4 + j) * 36 + n2 * 16 + l15] = accC[n2][j];
        __syncthreads();

        if (b == 0) carry = linT[l15 * 36];   // lin[row, 0] for neuron 0

        // --- serial 32 steps, rank-1 updates, history packed to hist ---
        float acc[32];
        #pragma unroll
        for (int j = 0; j < 32; ++j) acc[j] = 0.0f;
        float lastlin = carry;
        const float* wcb = wcol + b * 496;
        #pragma unroll
        for (int u8 = 0; u8 < 4; ++u8) {
            float4 cw0 = *reinterpret_cast<const float4*>(&conT[l15 * 36 + u8 * 8]);
            float4 cw1 = *reinterpret_cast<const float4*>(&conT[l15 * 36 + u8 * 8 + 4]);
            float4 lw0 = *reinterpret_cast<const float4*>(&linT[l15 * 36 + u8 * 8]);
            float4 lw1 = *reinterpret_cast<const float4*>(&linT[l15 * 36 + u8 * 8 + 4]);
            float conw[8] = {cw0.x, cw0.y, cw0.z, cw0.w, cw1.x, cw1.y, cw1.z, cw1.w};
            float linw[8] = {lw0.x, lw0.y, lw0.z, lw0.w, lw1.x, lw1.y, lw1.z, lw1.w};
            unsigned int pk[8];
            #pragma unroll
            for (int v = 0; v < 8; ++v) {
                const int u = u8 * 8 + v;
                float lv = (v == 0) ? lastlin : linw[v - 1];
                float vv = acc[u] + conw[v] + lv + 1.0f;
                float tv = fast_tanh(vv);
                _Float16 hv = (_Float16)tv;
                _Float16 lo = (_Float16)(tv - (float)hv);
                pk[v] = (unsigned int)h2u(hv) | ((unsigned int)h2u(lo) << 16);
                const float* wu = wcb + (31 * u - (u * (u - 1)) / 2);
                #pragma unroll
                for (int j = u + 1; j < 32; ++j)
                    acc[j] = fmaf(tv, wu[j - u - 1], acc[j]);
            }
            lastlin = linw[7];
            if (l < 16) {
                *reinterpret_cast<u32x4*>(histc + hrow + b * 32 + u8 * 8) =
                    (u32x4){pk[0], pk[1], pk[2], pk[3]};
                *reinterpret_cast<u32x4*>(histc + hrow + b * 32 + u8 * 8 + 4) =
                    (u32x4){pk[4], pk[5], pk[6], pk[7]};
            }
        }
        carry = lastlin;
        __syncthreads();   // drains vmcnt: hist stores visible to next block's reads
    }

    // ===== stage 3: out = tanh @ W_out^T + lin_o + 1 (A-frags from hist) =====
    #pragma unroll
    for (int n = 0; n < 4; ++n) {
        f32x4 acc = (f32x4){0.f, 0.f, 0.f, 0.f};
        #pragma unroll
        for (int kc = 0; kc < 8; ++kc) {
            f16x8 ah, al;
            hist_frag(histc + hrow + kc * 32 + g * 8, &ah, &al);
            const size_t wrow = (size_t)(n * 16 + l15) * 256 + kc * 32 + g * 8;
            f16x8 bh = __builtin_bit_cast(f16x8, *reinterpret_cast<const u16x8*>(wout_h + wrow));
            f16x8 bl = __builtin_bit_cast(f16x8, *reinterpret_cast<const u16x8*>(wout_l + wrow));
            acc = __builtin_amdgcn_mfma_f32_16x16x32_f16(ah, bh, acc, 0, 0, 0);
            acc = __builtin_amdgcn_mfma_f32_16x16x32_f16(al, bh, acc, 0, 0, 0);
            acc = __builtin_amdgcn_mfma_f32_16x16x32_f16(ah, bl, acc, 0, 0, 0);
        }
        #pragma unroll
        for (int j = 0; j < 4; ++j) {
            long r = row0 + g * 4 + j;
            int c = n * 16 + l15;
            out[r * 64 + c] = acc[j] + lino[r * 64 + c] + 1.0f;
        }
    }
}

extern "C" void kernel_launch(void* const* d_in, const int* in_sizes, int n_in,
                              void* d_out, int out_size, void* d_ws, size_t ws_size,
                              hipStream_t stream) {
    (void)in_sizes; (void)n_in; (void)out_size; (void)ws_size;
    const float* x     = (const float*)d_in[0];
    const float* W_lin = (const float*)d_in[1];
    const float* W_nl  = (const float*)d_in[2];
    const float* W_out = (const float*)d_in[3];
    float* out = (float*)d_out;

    char* ws = (char*)d_ws;
    unsigned short* wlin_h = (unsigned short*)(ws);
    unsigned short* wlin_l = (unsigned short*)(ws + 327680);
    unsigned short* wnl_h  = (unsigned short*)(ws + 916480);
    unsigned short* wnl_l  = (unsigned short*)(ws + 1047040);
    unsigned short* wout_h = (unsigned short*)(ws + 1177600);
    unsigned short* wout_l = (unsigned short*)(ws + 1210368);
    float*          wcol   = (float*)(ws + 1243136);
    float*          linc   = (float*)(ws + 1259008);
    float*          lino   = (float*)(ws + 68367872);

    cascade_prep<<<256, 256, 0, stream>>>(W_lin, W_nl, W_out,
                                          wlin_h, wlin_l, wnl_h, wnl_l,
                                          wout_h, wout_l, wcol);
    lin_gemm<<<65536 / 32, 256, 0, stream>>>(x, wlin_h, wlin_l, linc, lino);
    cascade_casc<<<65536 / 16, 64, 0, stream>>>(linc, lino, wcol,
                                                wnl_h, wnl_l, wout_h, wout_l, out);
}

// Round 12
// 315.009 us; speedup vs baseline: 1.2520x; 1.0777x over previous
//
#include <hip/hip_runtime.h>
#include <hip/hip_bf16.h>

typedef _Float16 f16x8 __attribute__((ext_vector_type(8)));
typedef unsigned short u16x8 __attribute__((ext_vector_type(8)));
typedef float f32x4 __attribute__((ext_vector_type(4)));
typedef unsigned int u32x4 __attribute__((ext_vector_type(4)));

static __device__ __forceinline__ unsigned short h2u(_Float16 h) {
    return __builtin_bit_cast(unsigned short, h);
}
static __device__ __forceinline__ float fast_tanh(float x) {
    float e = __expf(2.0f * x);
    return 1.0f - 2.0f / (e + 1.0f);
}

// ---------------- ws layout (bytes) ----------------
//   wlin_h : u16 [320][512]   @ 0        (327680)
//   wlin_l : u16 [320][512]   @ 327680   (327680)
//   (unused)                  @ 655360   (261120)
//   wnl_h  : u16 [255][256]   @ 916480   (130560)
//   wnl_l  : u16 [255][256]   @ 1047040  (130560)
//   wout_h : u16 [64][256]    @ 1177600  (32768)
//   wout_l : u16 [64][256]    @ 1210368  (32768)
//   wcol   : f32 [8][496]     @ 1243136  (15872)   column-transposed triangles
//   linc   : f32 [65536][256] @ 1259008  (67108864)  (overlaid by packed hist)
//   lino   : f32 [65536][64]  @ 68367872 (16777216)  total 85145088
__global__ void cascade_prep(const float* __restrict__ W_lin,
                             const float* __restrict__ W_nl,
                             const float* __restrict__ W_out,
                             unsigned short* __restrict__ wlin_h,
                             unsigned short* __restrict__ wlin_l,
                             unsigned short* __restrict__ wnl_h,
                             unsigned short* __restrict__ wnl_l,
                             unsigned short* __restrict__ wout_h,
                             unsigned short* __restrict__ wout_l,
                             float* __restrict__ wcol) {
    int idx = blockIdx.x * blockDim.x + threadIdx.x;
    int stride = gridDim.x * blockDim.x;
    for (int i = idx; i < 320 * 512; i += stride) {
        int n = i >> 9, k = i & 511;
        float w = W_lin[k * 320 + n];
        _Float16 h = (_Float16)w;
        wlin_h[i] = h2u(h);
        wlin_l[i] = h2u((_Float16)(w - (float)h));
    }
    for (int i = idx; i < 255 * 256; i += stride) {
        int r = i >> 8, k = i & 255;
        float w = (k <= r) ? W_nl[i] : 0.0f;
        _Float16 h = (_Float16)w;
        wnl_h[i] = h2u(h);
        wnl_l[i] = h2u((_Float16)(w - (float)h));
    }
    for (int i = idx; i < 64 * 256; i += stride) {
        float w = W_out[i];
        _Float16 h = (_Float16)w;
        wout_h[i] = h2u(h);
        wout_l[i] = h2u((_Float16)(w - (float)h));
    }
    // column-transposed intra-block triangles:
    // wcol[b][31u - u(u-1)/2 + (j-u-1)] = W_nl[32b+j-1][32b+u], j in (u,32)
    for (int i = idx; i < 256; i += stride) {
        int b = i >> 5, u = i & 31;
        float* dst = wcol + b * 496 + (31 * u - (u * (u - 1)) / 2);
        for (int j = u + 1; j < 32; ++j)
            dst[j - u - 1] = W_nl[(size_t)(b * 32 + j - 1) * 256 + b * 32 + u];
    }
}

// ---------------- kernel A: lin = x @ W_lin (fp16-split), writes linc/lino ----------------
__global__ __launch_bounds__(256, 2) void lin_gemm(
    const float* __restrict__ x,
    const unsigned short* __restrict__ wlin_h,
    const unsigned short* __restrict__ wlin_l,
    float* __restrict__ linc,
    float* __restrict__ lino) {

    __shared__ _Float16 xh[32 * 520];
    __shared__ _Float16 xl[32 * 520];

    const int tid = threadIdx.x;
    const int wv  = tid >> 6;
    const int l15 = tid & 15;
    const int g   = (tid & 63) >> 4;
    const long row0 = (long)blockIdx.x * 32;

    #pragma unroll
    for (int it = 0; it < 16; ++it) {
        int flat = it * 1024 + tid * 4;
        int r = flat >> 9, c = flat & 511;
        float4 v = *reinterpret_cast<const float4*>(x + (row0 + r) * 512 + c);
        _Float16 h0 = (_Float16)v.x, h1 = (_Float16)v.y, h2 = (_Float16)v.z, h3 = (_Float16)v.w;
        ushort4 uh = { h2u(h0), h2u(h1), h2u(h2), h2u(h3) };
        ushort4 ul = { h2u((_Float16)(v.x - (float)h0)), h2u((_Float16)(v.y - (float)h1)),
                       h2u((_Float16)(v.z - (float)h2)), h2u((_Float16)(v.w - (float)h3)) };
        *reinterpret_cast<ushort4*>(xh + r * 520 + c) = uh;
        *reinterpret_cast<ushort4*>(xl + r * 520 + c) = ul;
    }
    __syncthreads();

    f32x4 acc[2][5];
    #pragma unroll
    for (int m = 0; m < 2; ++m)
        #pragma unroll
        for (int ti = 0; ti < 5; ++ti) acc[m][ti] = (f32x4){0.f, 0.f, 0.f, 0.f};

    for (int half = 0; half < 2; ++half) {
        f16x8 ah[2][8], al[2][8];
        #pragma unroll
        for (int m = 0; m < 2; ++m)
            #pragma unroll
            for (int k8 = 0; k8 < 8; ++k8) {
                int off = (m * 16 + l15) * 520 + g * 8 + (half * 8 + k8) * 32;
                ah[m][k8] = *reinterpret_cast<const f16x8*>(xh + off);
                al[m][k8] = *reinterpret_cast<const f16x8*>(xl + off);
            }
        #pragma unroll
        for (int ti = 0; ti < 5; ++ti) {
            int n = wv + ti * 4;
            const unsigned short* bhp = wlin_h + (size_t)(n * 16 + l15) * 512 + g * 8 + half * 256;
            const unsigned short* blp = wlin_l + (size_t)(n * 16 + l15) * 512 + g * 8 + half * 256;
            #pragma unroll
            for (int k8 = 0; k8 < 8; ++k8) {
                f16x8 bh = __builtin_bit_cast(f16x8, *reinterpret_cast<const u16x8*>(bhp + k8 * 32));
                #pragma unroll
                for (int m = 0; m < 2; ++m)
                    acc[m][ti] = __builtin_amdgcn_mfma_f32_16x16x32_f16(ah[m][k8], bh, acc[m][ti], 0, 0, 0);
                if (ti < 4) {
                    f16x8 bl = __builtin_bit_cast(f16x8, *reinterpret_cast<const u16x8*>(blp + k8 * 32));
                    #pragma unroll
                    for (int m = 0; m < 2; ++m) {
                        acc[m][ti] = __builtin_amdgcn_mfma_f32_16x16x32_f16(al[m][k8], bh, acc[m][ti], 0, 0, 0);
                        acc[m][ti] = __builtin_amdgcn_mfma_f32_16x16x32_f16(ah[m][k8], bl, acc[m][ti], 0, 0, 0);
                    }
                }
            }
        }
    }
    #pragma unroll
    for (int m = 0; m < 2; ++m) {
        #pragma unroll
        for (int ti = 0; ti < 4; ++ti) {
            int c = (wv + ti * 4) * 16 + l15;
            #pragma unroll
            for (int j = 0; j < 4; ++j)
                linc[(row0 + m * 16 + g * 4 + j) * 256 + c] = acc[m][ti][j];
        }
        int c = wv * 16 + l15;
        #pragma unroll
        for (int j = 0; j < 4; ++j)
            lino[(row0 + m * 16 + g * 4 + j) * 64 + c] = acc[m][4][j];
    }
}

// unpack 8 packed h|l u32 columns -> fp16 hi / lo MFMA A-fragments
static __device__ __forceinline__ void hist_frag(const unsigned int* hp,
                                                 f16x8* ah, f16x8* al) {
    u32x4 a0 = *reinterpret_cast<const u32x4*>(hp);
    u32x4 a1 = *reinterpret_cast<const u32x4*>(hp + 4);
    u32x4 hx, lx;
    hx[0] = (a0[0] & 0xffffu) | (a0[1] << 16);
    hx[1] = (a0[2] & 0xffffu) | (a0[3] << 16);
    hx[2] = (a1[0] & 0xffffu) | (a1[1] << 16);
    hx[3] = (a1[2] & 0xffffu) | (a1[3] << 16);
    lx[0] = (a0[0] >> 16) | (a0[1] & 0xffff0000u);
    lx[1] = (a0[2] >> 16) | (a0[3] & 0xffff0000u);
    lx[2] = (a1[0] >> 16) | (a1[1] & 0xffff0000u);
    lx[3] = (a1[2] >> 16) | (a1[3] & 0xffff0000u);
    *ah = __builtin_bit_cast(f16x8, hx);
    *al = __builtin_bit_cast(f16x8, lx);
}

// ---------------- kernel B: cascade + output GEMM ----------------
// 1 wave, 32 rows/block (2x less serial replication than r11). Grid 2048 ->
// 8 blocks/CU (2 waves/SIMD), one resident round. LDS: conT/linT [32][36] +
// wcol slab [500] = 11200 B. Serial: lane owns row l&31 (2 replicas, halves
// the r11 4x-redundant VALU); scatter weights come from LDS (broadcast
// ds_read, no 64-bit flat-address VALU per FMA).
__global__ __launch_bounds__(64, 2) void cascade_casc(
    float* linc,                        // f32 lin in, packed hist out (aliased!)
    const float* __restrict__ lino,
    const float* __restrict__ wcol,
    const unsigned short* __restrict__ wnl_h,
    const unsigned short* __restrict__ wnl_l,
    const unsigned short* __restrict__ wout_h,
    const unsigned short* __restrict__ wout_l,
    float* __restrict__ out) {

    __shared__ float conT[32 * 36];   // [row][u] contrib window
    __shared__ float linT[32 * 36];   // [row][u] lin window
    __shared__ float wslab[500];      // current block's column-triangle slab

    const int l   = threadIdx.x;
    const int l15 = l & 15;
    const int g   = l >> 4;          // MFMA k-group
    const int r   = l & 31;          // serial-phase batch row (2 replicas)
    const long row0 = (long)blockIdx.x * 32;

    unsigned int* histc = reinterpret_cast<unsigned int*>(linc);
    float carry = 0.0f;

    for (int b = 0; b < 8; ++b) {
        // --- stage lin window [32 rows][32 cols] + wcol slab -> LDS ---
        #pragma unroll
        for (int it = 0; it < 4; ++it) {
            int flat = it * 256 + l * 4;       // 1024 floats
            int rr = flat >> 5, c4 = flat & 31;
            float4 v = *reinterpret_cast<const float4*>(
                linc + (row0 + rr) * 256 + b * 32 + c4);
            *reinterpret_cast<float4*>(&linT[rr * 36 + c4]) = v;
        }
        {
            int i0 = l * 4;
            if (i0 < 496) {
                float4 v = *reinterpret_cast<const float4*>(wcol + b * 496 + i0);
                *reinterpret_cast<float4*>(&wslab[i0]) = v;
            }
            int i1 = 256 + l * 4;
            if (i1 < 496) {
                float4 v = *reinterpret_cast<const float4*>(wcol + b * 496 + i1);
                *reinterpret_cast<float4*>(&wslab[i1]) = v;
            }
        }

        // --- inter-block contribution GEMM (K = 32b), 2 m-tiles ---
        f32x4 accC[2][2];
        #pragma unroll
        for (int m = 0; m < 2; ++m)
            #pragma unroll
            for (int n2 = 0; n2 < 2; ++n2)
                accC[m][n2] = (f32x4){0.f, 0.f, 0.f, 0.f};
        for (int kc = 0; kc < b; ++kc) {
            f16x8 ah[2], al[2];
            #pragma unroll
            for (int m = 0; m < 2; ++m)
                hist_frag(histc + (row0 + m * 16 + l15) * 256 + kc * 32 + g * 8,
                          &ah[m], &al[m]);
            #pragma unroll
            for (int n2 = 0; n2 < 2; ++n2) {
                const size_t wrow = (size_t)(b * 32 + n2 * 16 + l15 - 1) * 256 + kc * 32 + g * 8;
                f16x8 bh = __builtin_bit_cast(f16x8, *reinterpret_cast<const u16x8*>(wnl_h + wrow));
                f16x8 bl = __builtin_bit_cast(f16x8, *reinterpret_cast<const u16x8*>(wnl_l + wrow));
                #pragma unroll
                for (int m = 0; m < 2; ++m) {
                    accC[m][n2] = __builtin_amdgcn_mfma_f32_16x16x32_f16(ah[m], bh, accC[m][n2], 0, 0, 0);
                    accC[m][n2] = __builtin_amdgcn_mfma_f32_16x16x32_f16(al[m], bh, accC[m][n2], 0, 0, 0);
                    accC[m][n2] = __builtin_amdgcn_mfma_f32_16x16x32_f16(ah[m], bl, accC[m][n2], 0, 0, 0);
                }
            }
        }
        // bounce D-frags -> conT[row][col]
        #pragma unroll
        for (int m = 0; m < 2; ++m)
            #pragma unroll
            for (int n2 = 0; n2 < 2; ++n2)
                #pragma unroll
                for (int j = 0; j < 4; ++j)
                    conT[(m * 16 + g * 4 + j) * 36 + n2 * 16 + l15] = accC[m][n2][j];
        __syncthreads();

        if (b == 0) carry = linT[r * 36];   // lin[row, 0] for neuron 0

        // --- serial 32 steps, rank-1 updates, weights from LDS ---
        float acc[32];
        #pragma unroll
        for (int j = 0; j < 32; ++j) acc[j] = 0.0f;
        float lastlin = carry;
        #pragma unroll
        for (int u8 = 0; u8 < 4; ++u8) {
            float4 cw0 = *reinterpret_cast<const float4*>(&conT[r * 36 + u8 * 8]);
            float4 cw1 = *reinterpret_cast<const float4*>(&conT[r * 36 + u8 * 8 + 4]);
            float4 lw0 = *reinterpret_cast<const float4*>(&linT[r * 36 + u8 * 8]);
            float4 lw1 = *reinterpret_cast<const float4*>(&linT[r * 36 + u8 * 8 + 4]);
            float conw[8] = {cw0.x, cw0.y, cw0.z, cw0.w, cw1.x, cw1.y, cw1.z, cw1.w};
            float linw[8] = {lw0.x, lw0.y, lw0.z, lw0.w, lw1.x, lw1.y, lw1.z, lw1.w};
            unsigned int pk[8];
            #pragma unroll
            for (int v = 0; v < 8; ++v) {
                const int u = u8 * 8 + v;
                float lv = (v == 0) ? lastlin : linw[v - 1];
                float vv = acc[u] + conw[v] + lv + 1.0f;
                float tv = fast_tanh(vv);
                _Float16 hv = (_Float16)tv;
                _Float16 lo = (_Float16)(tv - (float)hv);
                pk[v] = (unsigned int)h2u(hv) | ((unsigned int)h2u(lo) << 16);
                const float* wu = wslab + (31 * u - (u * (u - 1)) / 2);
                #pragma unroll
                for (int j = u + 1; j < 32; ++j)
                    acc[j] = fmaf(tv, wu[j - u - 1], acc[j]);
            }
            lastlin = linw[7];
            if (l < 32) {
                long hb = (row0 + r) * 256 + b * 32 + u8 * 8;
                *reinterpret_cast<u32x4*>(histc + hb) = (u32x4){pk[0], pk[1], pk[2], pk[3]};
                *reinterpret_cast<u32x4*>(histc + hb + 4) = (u32x4){pk[4], pk[5], pk[6], pk[7]};
            }
        }
        carry = lastlin;
        __syncthreads();   // hist stores visible; LDS safe to overwrite
    }

    // ===== stage 3: out = tanh @ W_out^T + lin_o + 1 (A-frags from hist) =====
    #pragma unroll
    for (int m = 0; m < 2; ++m) {
        #pragma unroll
        for (int n = 0; n < 4; ++n) {
            f32x4 acc = (f32x4){0.f, 0.f, 0.f, 0.f};
            #pragma unroll
            for (int kc = 0; kc < 8; ++kc) {
                f16x8 ah, al;
                hist_frag(histc + (row0 + m * 16 + l15) * 256 + kc * 32 + g * 8, &ah, &al);
                const size_t wrow = (size_t)(n * 16 + l15) * 256 + kc * 32 + g * 8;
                f16x8 bh = __builtin_bit_cast(f16x8, *reinterpret_cast<const u16x8*>(wout_h + wrow));
                f16x8 bl = __builtin_bit_cast(f16x8, *reinterpret_cast<const u16x8*>(wout_l + wrow));
                acc = __builtin_amdgcn_mfma_f32_16x16x32_f16(ah, bh, acc, 0, 0, 0);
                acc = __builtin_amdgcn_mfma_f32_16x16x32_f16(al, bh, acc, 0, 0, 0);
                acc = __builtin_amdgcn_mfma_f32_16x16x32_f16(ah, bl, acc, 0, 0, 0);
            }
            #pragma unroll
            for (int j = 0; j < 4; ++j) {
                long rr = row0 + m * 16 + g * 4 + j;
                int c = n * 16 + l15;
                out[rr * 64 + c] = acc[j] + lino[rr * 64 + c] + 1.0f;
            }
        }
    }
}

extern "C" void kernel_launch(void* const* d_in, const int* in_sizes, int n_in,
                              void* d_out, int out_size, void* d_ws, size_t ws_size,
                              hipStream_t stream) {
    (void)in_sizes; (void)n_in; (void)out_size; (void)ws_size;
    const float* x     = (const float*)d_in[0];
    const float* W_lin = (const float*)d_in[1];
    const float* W_nl  = (const float*)d_in[2];
    const float* W_out = (const float*)d_in[3];
    float* out = (float*)d_out;

    char* ws = (char*)d_ws;
    unsigned short* wlin_h = (unsigned short*)(ws);
    unsigned short* wlin_l = (unsigned short*)(ws + 327680);
    unsigned short* wnl_h  = (unsigned short*)(ws + 916480);
    unsigned short* wnl_l  = (unsigned short*)(ws + 1047040);
    unsigned short* wout_h = (unsigned short*)(ws + 1177600);
    unsigned short* wout_l = (unsigned short*)(ws + 1210368);
    float*          wcol   = (float*)(ws + 1243136);
    float*          linc   = (float*)(ws + 1259008);
    float*          lino   = (float*)(ws + 68367872);

    cascade_prep<<<256, 256, 0, stream>>>(W_lin, W_nl, W_out,
                                          wlin_h, wlin_l, wnl_h, wnl_l,
                                          wout_h, wout_l, wcol);
    lin_gemm<<<65536 / 32, 256, 0, stream>>>(x, wlin_h, wlin_l, linc, lino);
    cascade_casc<<<65536 / 32, 64, 0, stream>>>(linc, lino, wcol,
                                                wnl_h, wnl_l, wout_h, wout_l, out);
}

// Round 13
// 245.651 us; speedup vs baseline: 1.6054x; 1.2823x over previous
//
#include <hip/hip_runtime.h>
#include <hip/hip_bf16.h>

typedef _Float16 f16x8 __attribute__((ext_vector_type(8)));
typedef unsigned short u16x8 __attribute__((ext_vector_type(8)));
typedef float f32x4 __attribute__((ext_vector_type(4)));
typedef unsigned int u32x4 __attribute__((ext_vector_type(4)));

static __device__ __forceinline__ unsigned short h2u(_Float16 h) {
    return __builtin_bit_cast(unsigned short, h);
}
static __device__ __forceinline__ float fast_tanh(float x) {
    float e = __expf(2.0f * x);
    return 1.0f - 2.0f / (e + 1.0f);
}

// ---------------- ws layout (bytes) ----------------
//   wlin_h : u16 [320][512]   @ 0        (327680)
//   wlin_l : u16 [320][512]   @ 327680   (327680)
//   (unused)                  @ 655360   (261120)
//   wnl_h  : u16 [255][256]   @ 916480   (130560)
//   wnl_l  : u16 [255][256]   @ 1047040  (130560)
//   wout_h : u16 [64][256]    @ 1177600  (32768)
//   wout_l : u16 [64][256]    @ 1210368  (32768)
//   wcol   : f32 [8][496]     @ 1243136  (15872)   column-transposed triangles
//   linc   : f32 [65536][256] @ 1259008  (67108864)  (overlaid by packed hist)
//   lino   : f32 [65536][64]  @ 68367872 (16777216)  total 85145088
__global__ void cascade_prep(const float* __restrict__ W_lin,
                             const float* __restrict__ W_nl,
                             const float* __restrict__ W_out,
                             unsigned short* __restrict__ wlin_h,
                             unsigned short* __restrict__ wlin_l,
                             unsigned short* __restrict__ wnl_h,
                             unsigned short* __restrict__ wnl_l,
                             unsigned short* __restrict__ wout_h,
                             unsigned short* __restrict__ wout_l,
                             float* __restrict__ wcol) {
    int idx = blockIdx.x * blockDim.x + threadIdx.x;
    int stride = gridDim.x * blockDim.x;
    for (int i = idx; i < 320 * 512; i += stride) {
        int n = i >> 9, k = i & 511;
        float w = W_lin[k * 320 + n];
        _Float16 h = (_Float16)w;
        wlin_h[i] = h2u(h);
        wlin_l[i] = h2u((_Float16)(w - (float)h));
    }
    for (int i = idx; i < 255 * 256; i += stride) {
        int r = i >> 8, k = i & 255;
        float w = (k <= r) ? W_nl[i] : 0.0f;
        _Float16 h = (_Float16)w;
        wnl_h[i] = h2u(h);
        wnl_l[i] = h2u((_Float16)(w - (float)h));
    }
    for (int i = idx; i < 64 * 256; i += stride) {
        float w = W_out[i];
        _Float16 h = (_Float16)w;
        wout_h[i] = h2u(h);
        wout_l[i] = h2u((_Float16)(w - (float)h));
    }
    // column-transposed intra-block triangles:
    // wcol[b][31u - u(u-1)/2 + (j-u-1)] = W_nl[32b+j-1][32b+u], j in (u,32)
    for (int i = idx; i < 256; i += stride) {
        int b = i >> 5, u = i & 31;
        float* dst = wcol + b * 496 + (31 * u - (u * (u - 1)) / 2);
        for (int j = u + 1; j < 32; ++j)
            dst[j - u - 1] = W_nl[(size_t)(b * 32 + j - 1) * 256 + b * 32 + u];
    }
}

// ---------------- kernel A: lin = x @ W_lin (fp16-split) ----------------
// v2: 512 threads (8 waves), M = 128 rows/block, 512 blocks.
// x in REGISTERS per wave (128 VGPR, no x-LDS, no staging sync).
// B double-buffered in LDS (padded stride 520 -> conflict-free), staged once
// per n-tile per block: T14 split — global loads for nt+1 issued BEFORE
// compute(nt), ds_write after, one barrier per n-tile.
__global__ __launch_bounds__(512, 1) void lin_gemm(
    const float* __restrict__ x,
    const unsigned short* __restrict__ wlin_h,
    const unsigned short* __restrict__ wlin_l,
    float* __restrict__ linc,
    float* __restrict__ lino) {

    __shared__ _Float16 bufH[2][16 * 520];   // 2 x 16.25 KB
    __shared__ _Float16 bufL[2][16 * 520];   // 2 x 16.25 KB   total 65 KB

    const int tid = threadIdx.x;
    const int wv  = tid >> 6;        // 0..7
    const int l15 = tid & 15;
    const int g   = (tid & 63) >> 4;
    const long row0 = (long)blockIdx.x * 128;

    // ===== x -> fp16 h/l A-fragments in registers (wave's own 16 rows) =====
    f16x8 xfh[16], xfl[16];
    {
        const float* xp = x + (row0 + wv * 16 + l15) * 512 + g * 8;
        #pragma unroll
        for (int ks = 0; ks < 16; ++ks) {
            float4 p0 = *reinterpret_cast<const float4*>(xp + ks * 32);
            float4 p1 = *reinterpret_cast<const float4*>(xp + ks * 32 + 4);
            float av[8] = {p0.x, p0.y, p0.z, p0.w, p1.x, p1.y, p1.z, p1.w};
            f16x8 fh, fl;
            #pragma unroll
            for (int e = 0; e < 8; ++e) {
                _Float16 hh = (_Float16)av[e];
                fh[e] = hh;
                fl[e] = (_Float16)(av[e] - (float)hh);
            }
            xfh[ks] = fh;
            xfl[ks] = fl;
        }
    }

    // staging: tile nt = 16 rows x 512 cols of wlin_h/wlin_l.
    // 8192 elems; 512 lanes x 8 elems -> 2 iters. Fully coalesced 16B/lane.
    u16x8 rh[2], rl[2];
    #define STAGE_LOAD(nt)                                                     \
        {                                                                      \
            _Pragma("unroll")                                                  \
            for (int it = 0; it < 2; ++it) {                                   \
                int flat = it * 4096 + tid * 8;                                \
                int r = flat >> 9, c = flat & 511;                             \
                rh[it] = *reinterpret_cast<const u16x8*>(                      \
                    wlin_h + (size_t)((nt) * 16 + r) * 512 + c);               \
                rl[it] = *reinterpret_cast<const u16x8*>(                      \
                    wlin_l + (size_t)((nt) * 16 + r) * 512 + c);               \
            }                                                                  \
        }
    #define STAGE_WRITE(buf)                                                   \
        {                                                                      \
            _Pragma("unroll")                                                  \
            for (int it = 0; it < 2; ++it) {                                   \
                int flat = it * 4096 + tid * 8;                                \
                int r = flat >> 9, c = flat & 511;                             \
                *reinterpret_cast<u16x8*>(&bufH[buf][r * 520 + c]) =           \
                    __builtin_bit_cast(u16x8, rh[it]);                         \
                *reinterpret_cast<u16x8*>(&bufL[buf][r * 520 + c]) =           \
                    __builtin_bit_cast(u16x8, rl[it]);                         \
            }                                                                  \
        }

    STAGE_LOAD(0);
    STAGE_WRITE(0);
    __syncthreads();

    int cur = 0;
    for (int nt = 0; nt < 20; ++nt) {
        if (nt < 19) STAGE_LOAD(nt + 1);   // T14: issue early, land later

        f32x4 acc = (f32x4){0.f, 0.f, 0.f, 0.f};
        if (nt < 16) {
            #pragma unroll
            for (int ks = 0; ks < 16; ++ks) {
                f16x8 bh = *reinterpret_cast<const f16x8*>(
                    &bufH[cur][l15 * 520 + ks * 32 + g * 8]);
                f16x8 bl = *reinterpret_cast<const f16x8*>(
                    &bufL[cur][l15 * 520 + ks * 32 + g * 8]);
                acc = __builtin_amdgcn_mfma_f32_16x16x32_f16(xfh[ks], bh, acc, 0, 0, 0);
                acc = __builtin_amdgcn_mfma_f32_16x16x32_f16(xfl[ks], bh, acc, 0, 0, 0);
                acc = __builtin_amdgcn_mfma_f32_16x16x32_f16(xfh[ks], bl, acc, 0, 0, 0);
            }
            #pragma unroll
            for (int j = 0; j < 4; ++j)
                linc[(row0 + wv * 16 + g * 4 + j) * 256 + nt * 16 + l15] = acc[j];
        } else {
            #pragma unroll
            for (int ks = 0; ks < 16; ++ks) {
                f16x8 bh = *reinterpret_cast<const f16x8*>(
                    &bufH[cur][l15 * 520 + ks * 32 + g * 8]);
                acc = __builtin_amdgcn_mfma_f32_16x16x32_f16(xfh[ks], bh, acc, 0, 0, 0);
            }
            #pragma unroll
            for (int j = 0; j < 4; ++j)
                lino[(row0 + wv * 16 + g * 4 + j) * 64 + (nt - 16) * 16 + l15] = acc[j];
        }

        if (nt < 19) STAGE_WRITE(cur ^ 1);   // readers of buf[cur^1] passed last barrier
        __syncthreads();
        cur ^= 1;
    }
    #undef STAGE_LOAD
    #undef STAGE_WRITE
}

// unpack 8 packed h|l u32 columns -> fp16 hi / lo MFMA A-fragments
static __device__ __forceinline__ void hist_frag(const unsigned int* hp,
                                                 f16x8* ah, f16x8* al) {
    u32x4 a0 = *reinterpret_cast<const u32x4*>(hp);
    u32x4 a1 = *reinterpret_cast<const u32x4*>(hp + 4);
    u32x4 hx, lx;
    hx[0] = (a0[0] & 0xffffu) | (a0[1] << 16);
    hx[1] = (a0[2] & 0xffffu) | (a0[3] << 16);
    hx[2] = (a1[0] & 0xffffu) | (a1[1] << 16);
    hx[3] = (a1[2] & 0xffffu) | (a1[3] << 16);
    lx[0] = (a0[0] >> 16) | (a0[1] & 0xffff0000u);
    lx[1] = (a0[2] >> 16) | (a0[3] & 0xffff0000u);
    lx[2] = (a1[0] >> 16) | (a1[1] & 0xffff0000u);
    lx[3] = (a1[2] >> 16) | (a1[3] & 0xffff0000u);
    *ah = __builtin_bit_cast(f16x8, hx);
    *al = __builtin_bit_cast(f16x8, lx);
}

// ---------------- kernel B: cascade + output GEMM (unchanged from r12) ----------------
__global__ __launch_bounds__(64, 2) void cascade_casc(
    float* linc,                        // f32 lin in, packed hist out (aliased!)
    const float* __restrict__ lino,
    const float* __restrict__ wcol,
    const unsigned short* __restrict__ wnl_h,
    const unsigned short* __restrict__ wnl_l,
    const unsigned short* __restrict__ wout_h,
    const unsigned short* __restrict__ wout_l,
    float* __restrict__ out) {

    __shared__ float conT[32 * 36];   // [row][u] contrib window
    __shared__ float linT[32 * 36];   // [row][u] lin window
    __shared__ float wslab[500];      // current block's column-triangle slab

    const int l   = threadIdx.x;
    const int l15 = l & 15;
    const int g   = l >> 4;          // MFMA k-group
    const int r   = l & 31;          // serial-phase batch row (2 replicas)
    const long row0 = (long)blockIdx.x * 32;

    unsigned int* histc = reinterpret_cast<unsigned int*>(linc);
    float carry = 0.0f;

    for (int b = 0; b < 8; ++b) {
        // --- stage lin window [32 rows][32 cols] + wcol slab -> LDS ---
        #pragma unroll
        for (int it = 0; it < 4; ++it) {
            int flat = it * 256 + l * 4;       // 1024 floats
            int rr = flat >> 5, c4 = flat & 31;
            float4 v = *reinterpret_cast<const float4*>(
                linc + (row0 + rr) * 256 + b * 32 + c4);
            *reinterpret_cast<float4*>(&linT[rr * 36 + c4]) = v;
        }
        {
            int i0 = l * 4;
            if (i0 < 496) {
                float4 v = *reinterpret_cast<const float4*>(wcol + b * 496 + i0);
                *reinterpret_cast<float4*>(&wslab[i0]) = v;
            }
            int i1 = 256 + l * 4;
            if (i1 < 496) {
                float4 v = *reinterpret_cast<const float4*>(wcol + b * 496 + i1);
                *reinterpret_cast<float4*>(&wslab[i1]) = v;
            }
        }

        // --- inter-block contribution GEMM (K = 32b), 2 m-tiles ---
        f32x4 accC[2][2];
        #pragma unroll
        for (int m = 0; m < 2; ++m)
            #pragma unroll
            for (int n2 = 0; n2 < 2; ++n2)
                accC[m][n2] = (f32x4){0.f, 0.f, 0.f, 0.f};
        for (int kc = 0; kc < b; ++kc) {
            f16x8 ah[2], al[2];
            #pragma unroll
            for (int m = 0; m < 2; ++m)
                hist_frag(histc + (row0 + m * 16 + l15) * 256 + kc * 32 + g * 8,
                          &ah[m], &al[m]);
            #pragma unroll
            for (int n2 = 0; n2 < 2; ++n2) {
                const size_t wrow = (size_t)(b * 32 + n2 * 16 + l15 - 1) * 256 + kc * 32 + g * 8;
                f16x8 bh = __builtin_bit_cast(f16x8, *reinterpret_cast<const u16x8*>(wnl_h + wrow));
                f16x8 bl = __builtin_bit_cast(f16x8, *reinterpret_cast<const u16x8*>(wnl_l + wrow));
                #pragma unroll
                for (int m = 0; m < 2; ++m) {
                    accC[m][n2] = __builtin_amdgcn_mfma_f32_16x16x32_f16(ah[m], bh, accC[m][n2], 0, 0, 0);
                    accC[m][n2] = __builtin_amdgcn_mfma_f32_16x16x32_f16(al[m], bh, accC[m][n2], 0, 0, 0);
                    accC[m][n2] = __builtin_amdgcn_mfma_f32_16x16x32_f16(ah[m], bl, accC[m][n2], 0, 0, 0);
                }
            }
        }
        // bounce D-frags -> conT[row][col]
        #pragma unroll
        for (int m = 0; m < 2; ++m)
            #pragma unroll
            for (int n2 = 0; n2 < 2; ++n2)
                #pragma unroll
                for (int j = 0; j < 4; ++j)
                    conT[(m * 16 + g * 4 + j) * 36 + n2 * 16 + l15] = accC[m][n2][j];
        __syncthreads();

        if (b == 0) carry = linT[r * 36];   // lin[row, 0] for neuron 0

        // --- serial 32 steps, rank-1 updates, weights from LDS ---
        float acc[32];
        #pragma unroll
        for (int j = 0; j < 32; ++j) acc[j] = 0.0f;
        float lastlin = carry;
        #pragma unroll
        for (int u8 = 0; u8 < 4; ++u8) {
            float4 cw0 = *reinterpret_cast<const float4*>(&conT[r * 36 + u8 * 8]);
            float4 cw1 = *reinterpret_cast<const float4*>(&conT[r * 36 + u8 * 8 + 4]);
            float4 lw0 = *reinterpret_cast<const float4*>(&linT[r * 36 + u8 * 8]);
            float4 lw1 = *reinterpret_cast<const float4*>(&linT[r * 36 + u8 * 8 + 4]);
            float conw[8] = {cw0.x, cw0.y, cw0.z, cw0.w, cw1.x, cw1.y, cw1.z, cw1.w};
            float linw[8] = {lw0.x, lw0.y, lw0.z, lw0.w, lw1.x, lw1.y, lw1.z, lw1.w};
            unsigned int pk[8];
            #pragma unroll
            for (int v = 0; v < 8; ++v) {
                const int u = u8 * 8 + v;
                float lv = (v == 0) ? lastlin : linw[v - 1];
                float vv = acc[u] + conw[v] + lv + 1.0f;
                float tv = fast_tanh(vv);
                _Float16 hv = (_Float16)tv;
                _Float16 lo = (_Float16)(tv - (float)hv);
                pk[v] = (unsigned int)h2u(hv) | ((unsigned int)h2u(lo) << 16);
                const float* wu = wslab + (31 * u - (u * (u - 1)) / 2);
                #pragma unroll
                for (int j = u + 1; j < 32; ++j)
                    acc[j] = fmaf(tv, wu[j - u - 1], acc[j]);
            }
            lastlin = linw[7];
            if (l < 32) {
                long hb = (row0 + r) * 256 + b * 32 + u8 * 8;
                *reinterpret_cast<u32x4*>(histc + hb) = (u32x4){pk[0], pk[1], pk[2], pk[3]};
                *reinterpret_cast<u32x4*>(histc + hb + 4) = (u32x4){pk[4], pk[5], pk[6], pk[7]};
            }
        }
        carry = lastlin;
        __syncthreads();   // hist stores visible; LDS safe to overwrite
    }

    // ===== stage 3: out = tanh @ W_out^T + lin_o + 1 (A-frags from hist) =====
    #pragma unroll
    for (int m = 0; m < 2; ++m) {
        #pragma unroll
        for (int n = 0; n < 4; ++n) {
            f32x4 acc = (f32x4){0.f, 0.f, 0.f, 0.f};
            #pragma unroll
            for (int kc = 0; kc < 8; ++kc) {
                f16x8 ah, al;
                hist_frag(histc + (row0 + m * 16 + l15) * 256 + kc * 32 + g * 8, &ah, &al);
                const size_t wrow = (size_t)(n * 16 + l15) * 256 + kc * 32 + g * 8;
                f16x8 bh = __builtin_bit_cast(f16x8, *reinterpret_cast<const u16x8*>(wout_h + wrow));
                f16x8 bl = __builtin_bit_cast(f16x8, *reinterpret_cast<const u16x8*>(wout_l + wrow));
                acc = __builtin_amdgcn_mfma_f32_16x16x32_f16(ah, bh, acc, 0, 0, 0);
                acc = __builtin_amdgcn_mfma_f32_16x16x32_f16(al, bh, acc, 0, 0, 0);
                acc = __builtin_amdgcn_mfma_f32_16x16x32_f16(ah, bl, acc, 0, 0, 0);
            }
            #pragma unroll
            for (int j = 0; j < 4; ++j) {
                long rr = row0 + m * 16 + g * 4 + j;
                int c = n * 16 + l15;
                out[rr * 64 + c] = acc[j] + lino[rr * 64 + c] + 1.0f;
            }
        }
    }
}

extern "C" void kernel_launch(void* const* d_in, const int* in_sizes, int n_in,
                              void* d_out, int out_size, void* d_ws, size_t ws_size,
                              hipStream_t stream) {
    (void)in_sizes; (void)n_in; (void)out_size; (void)ws_size;
    const float* x     = (const float*)d_in[0];
    const float* W_lin = (const float*)d_in[1];
    const float* W_nl  = (const float*)d_in[2];
    const float* W_out = (const float*)d_in[3];
    float* out = (float*)d_out;

    char* ws = (char*)d_ws;
    unsigned short* wlin_h = (unsigned short*)(ws);
    unsigned short* wlin_l = (unsigned short*)(ws + 327680);
    unsigned short* wnl_h  = (unsigned short*)(ws + 916480);
    unsigned short* wnl_l  = (unsigned short*)(ws + 1047040);
    unsigned short* wout_h = (unsigned short*)(ws + 1177600);
    unsigned short* wout_l = (unsigned short*)(ws + 1210368);
    float*          wcol   = (float*)(ws + 1243136);
    float*          linc   = (float*)(ws + 1259008);
    float*          lino   = (float*)(ws + 68367872);

    cascade_prep<<<256, 256, 0, stream>>>(W_lin, W_nl, W_out,
                                          wlin_h, wlin_l, wnl_h, wnl_l,
                                          wout_h, wout_l, wcol);
    lin_gemm<<<512, 512, 0, stream>>>(x, wlin_h, wlin_l, linc, lino);
    cascade_casc<<<65536 / 32, 64, 0, stream>>>(linc, lino, wcol,
                                                wnl_h, wnl_l, wout_h, wout_l, out);
}